// Round 5
// baseline (353.818 us; speedup 1.0000x reference)
//
#include <hip/hip_runtime.h>
#include <math.h>

#define B_N 262144
#define K_N 100
#define NPAD 112
#define D_N 384
#define EPS 1e-8f
#define MOM 0.95f
#define SEG_MAX 32

typedef __attribute__((ext_vector_type(8))) short short8;
typedef __attribute__((ext_vector_type(4))) float f32x4;

// workspace byte offsets
#define OFF_CPK   0          // 12*7*512 u16 = 86016 B : B-hi packed [kk][nt][frag]
#define OFF_NC64  86016      // K f64
#define OFF_CNT   86816
#define OFF_OFFS  87264
#define OFF_CUR   87712
#define OFF_FLAGN 88160
#define OFF_FLAGS 88224      // B u32 = 1048576
#define OFF_IDX   1136800    // B u32 = 1048576
#define OFF_PART  2185376    // K*seg*D f64

#define GLOAD_LDS(g, l) __builtin_amdgcn_global_load_lds( \
    (const __attribute__((address_space(1))) unsigned int*)(g), \
    (__attribute__((address_space(3))) unsigned int*)(l), 16, 0, 0)

// cpk u16 index for element (col, d): MFMA B-fragment order
__device__ __forceinline__ size_t cpk_idx(int col, int d) {
    int kk = d >> 5, r = d & 31, lg = r >> 3, j = r & 7;
    int nt = col >> 4, l15 = col & 15;
    return (size_t)((kk * 7 + nt) * 512) + lg * 128 + l15 * 8 + j;
}

__device__ __forceinline__ unsigned short bf16_rne(float x) {
    unsigned u = __float_as_uint(x);
    unsigned r = (u + 0x7fff + ((u >> 16) & 1)) >> 16;   // round-nearest-even
    return (unsigned short)r;
}

// ---- normalize centroids -> RNE bf16 into MFMA-fragment-ordered cpk (hi only) ----
__global__ void k_norm_c(const float* __restrict__ c, unsigned short* __restrict__ cpk,
                         double* __restrict__ nc64) {
    int col = blockIdx.x;
    int t = threadIdx.x;  // 128
    if (col >= K_N) {
        for (int d = t; d < D_N; d += 128) cpk[cpk_idx(col, d)] = 0;
        return;
    }
    const float* row = c + (size_t)col * D_N;
    double ss = 0.0;
    for (int d = t; d < D_N; d += 128) { double v = row[d]; ss += v * v; }
    __shared__ double red[2];
    for (int o = 32; o > 0; o >>= 1) ss += __shfl_down(ss, o);
    if ((t & 63) == 0) red[t >> 6] = ss;
    __syncthreads();
    double nc = fmax(sqrt(red[0] + red[1]), (double)EPS);
    if (t == 0) nc64[col] = nc;
    float inv = (float)(1.0 / nc);
    for (int d = t; d < D_N; d += 128)
        cpk[cpk_idx(col, d)] = bf16_rne(row[d] * inv);
}

__global__ void k_zero(int* cnt, int* flagn) {
    int t = threadIdx.x;
    if (t < K_N) cnt[t] = 0;
    if (t == 0) *flagn = 0;
}

// ---- split 2x8 floats into bf16 hi/lo (a = hi + lo to ~2^-17) + ss ----
__device__ __forceinline__ void splitA(float4 x0, float4 x1,
                                       short8& ah, short8& al, float& ss) {
    float xs[8] = {x0.x, x0.y, x0.z, x0.w, x1.x, x1.y, x1.z, x1.w};
#pragma unroll
    for (int j = 0; j < 8; j++) {
        float x = xs[j];
        unsigned xb = __float_as_uint(x);
        unsigned hb = xb & 0xffff0000u;
        float lf = x - __uint_as_float(hb);
        ah[j] = (short)(hb >> 16);
        al[j] = (short)bf16_rne(lf);
        ss = fmaf(x, x, ss);
    }
}

// ---- MFMA sims: whole B-hi resident in LDS, zero in-loop barriers ----
__global__ __launch_bounds__(512) void k_main(
    const float* __restrict__ e, const unsigned short* __restrict__ cpk,
    float* __restrict__ out_nov, float* __restrict__ out_cls,
    unsigned* __restrict__ flags, int* __restrict__ flagn) {
    __shared__ unsigned short sB[84 * 512];   // 86016 B = all of packed B-hi
    const int t = threadIdx.x;
    const int lane = t & 63;
    const int wid = t >> 6;                   // 8 waves
    const int l15 = lane & 15;
    const int lg = lane >> 4;
    const int rowbase = blockIdx.x * 256 + wid * 32;

    // stage all of B once (84 x 1KB chunks over 8 waves)
    for (int c = wid; c < 84; c += 8)
        GLOAD_LDS((const char*)cpk + c * 1024 + lane * 16,
                  (char*)sB + c * 1024);

    const float* a0p = e + (size_t)(rowbase + l15) * D_N + lg * 8;
    const float* a1p = a0p + (size_t)16 * D_N;

    f32x4 acc[2][7];
#pragma unroll
    for (int rt = 0; rt < 2; rt++)
#pragma unroll
        for (int nt = 0; nt < 7; nt++) acc[rt][nt] = f32x4{0.f, 0.f, 0.f, 0.f};

    float ss0 = 0.f, ss1 = 0.f;
    float4 a[2][4];
    a[0][0] = *(const float4*)(a0p);
    a[0][1] = *(const float4*)(a0p + 4);
    a[0][2] = *(const float4*)(a1p);
    a[0][3] = *(const float4*)(a1p + 4);
    __syncthreads();   // B staged (drains each wave's DMA) — the only barrier

#pragma unroll 4
    for (int kk = 0; kk < 12; kk++) {
        const int par = kk & 1;
        if (kk < 11) {
            const int ko = (kk + 1) * 32;
            a[par ^ 1][0] = *(const float4*)(a0p + ko);
            a[par ^ 1][1] = *(const float4*)(a0p + ko + 4);
            a[par ^ 1][2] = *(const float4*)(a1p + ko);
            a[par ^ 1][3] = *(const float4*)(a1p + ko + 4);
        }
        short8 ah0, al0, ah1, al1;
        splitA(a[par][0], a[par][1], ah0, al0, ss0);
        splitA(a[par][2], a[par][3], ah1, al1, ss1);
#pragma unroll
        for (int nt = 0; nt < 7; nt++) {
            short8 bh = *(const short8*)(sB + (kk * 7 + nt) * 512 + lane * 8);
            acc[0][nt] = __builtin_amdgcn_mfma_f32_16x16x32_bf16(ah0, bh, acc[0][nt], 0, 0, 0);
            acc[0][nt] = __builtin_amdgcn_mfma_f32_16x16x32_bf16(al0, bh, acc[0][nt], 0, 0, 0);
            acc[1][nt] = __builtin_amdgcn_mfma_f32_16x16x32_bf16(ah1, bh, acc[1][nt], 0, 0, 0);
            acc[1][nt] = __builtin_amdgcn_mfma_f32_16x16x32_bf16(al1, bh, acc[1][nt], 0, 0, 0);
        }
    }

    // row sum-of-squares
    ss0 += __shfl_xor(ss0, 16); ss0 += __shfl_xor(ss0, 32);
    ss1 += __shfl_xor(ss1, 16); ss1 += __shfl_xor(ss1, 32);
    const int rl = lg * 4 + (l15 & 3);
    float ssr0 = __shfl(ss0, rl);
    float ssr1 = __shfl(ss1, rl);

#pragma unroll
    for (int rt = 0; rt < 2; rt++) {
        float b0 = -3e38f, b1 = -3e38f, b2 = -3e38f, b3 = -3e38f;
        float s0 = -3e38f, s1 = -3e38f, s2 = -3e38f, s3 = -3e38f;
        int i0 = 0, i1 = 0, i2 = 0, i3 = 0, j0 = 0, j1 = 0, j2 = 0, j3 = 0;
#pragma unroll
        for (int nt = 0; nt < 7; nt++) {
            int cl = nt * 16 + l15;
            bool valid = cl < K_N;
            float v;
            v = valid ? acc[rt][nt][0] : -3e38f;
            if (v > b0) { s0 = b0; j0 = i0; b0 = v; i0 = cl; } else if (v > s0) { s0 = v; j0 = cl; }
            v = valid ? acc[rt][nt][1] : -3e38f;
            if (v > b1) { s1 = b1; j1 = i1; b1 = v; i1 = cl; } else if (v > s1) { s1 = v; j1 = cl; }
            v = valid ? acc[rt][nt][2] : -3e38f;
            if (v > b2) { s2 = b2; j2 = i2; b2 = v; i2 = cl; } else if (v > s2) { s2 = v; j2 = cl; }
            v = valid ? acc[rt][nt][3] : -3e38f;
            if (v > b3) { s3 = b3; j3 = i3; b3 = v; i3 = cl; } else if (v > s3) { s3 = v; j3 = cl; }
        }
#pragma unroll
        for (int w = 1; w <= 8; w <<= 1) {
#define MRG(B, S, I, J)                                                        \
            {                                                                  \
                float ob = __shfl_xor(B, w), os = __shfl_xor(S, w);            \
                int obi = __shfl_xor(I, w), osi = __shfl_xor(J, w);            \
                if (ob > B) {                                                  \
                    float ns; int nsi;                                         \
                    if (B > os) { ns = B; nsi = I; } else { ns = os; nsi = osi; } \
                    B = ob; I = obi; S = ns; J = nsi;                          \
                } else if (ob > S) { S = ob; J = obi; }                        \
            }
            MRG(b0, s0, i0, j0) MRG(b1, s1, i1, j1) MRG(b2, s2, i2, j2) MRG(b3, s3, i3, j3)
#undef MRG
        }
        if (l15 < 4) {
            float bb = (l15 & 2) ? ((l15 & 1) ? b3 : b2) : ((l15 & 1) ? b1 : b0);
            float sv = (l15 & 2) ? ((l15 & 1) ? s3 : s2) : ((l15 & 1) ? s1 : s0);
            int bi   = (l15 & 2) ? ((l15 & 1) ? i3 : i2) : ((l15 & 1) ? i1 : i0);
            int si   = (l15 & 2) ? ((l15 & 1) ? j3 : j2) : ((l15 & 1) ? j1 : j0);
            int grow = rowbase + rt * 16 + rl;
            float ssr = rt ? ssr1 : ssr0;
            float nrm = fmaxf(sqrtf(ssr), EPS);
            float msim = bb / nrm;
            out_nov[grow] = 1.f - msim * msim;
            out_cls[grow] = (float)bi;
            if (bb - sv < 1e-3f * nrm) {
                int pos = atomicAdd(flagn, 1);
                flags[pos] = ((unsigned)grow << 14) | ((unsigned)bi << 7) | (unsigned)si;
            }
        }
    }
}

// ---- cooperative fp64 refinement of flagged near-ties ----
__global__ void k_refine(const float* __restrict__ e, const float* __restrict__ c_raw,
                         const double* __restrict__ nc64, const int* __restrict__ flagn,
                         const unsigned* __restrict__ flags,
                         float* __restrict__ out_nov, float* __restrict__ out_cls) {
    int n = *flagn;
    int gw = (blockIdx.x * 256 + threadIdx.x) >> 6;
    int lane = threadIdx.x & 63;
    int nw = (gridDim.x * 256) >> 6;
    for (int i = gw; i < n; i += nw) {
        unsigned f = flags[i];
        int row = f >> 14, bi = (f >> 7) & 127, si = f & 127;
        const float* er = e + (size_t)row * D_N;
        const float* ca = c_raw + (size_t)bi * D_N;
        const float* cb = c_raw + (size_t)si * D_N;
        double d1 = 0, d2 = 0, ee = 0;
#pragma unroll
        for (int j = 0; j < 6; j++) {
            int d = lane * 6 + j;
            double ev = er[d];
            d1 += ev * (double)ca[d];
            d2 += ev * (double)cb[d];
            ee += ev * ev;
        }
#pragma unroll
        for (int w = 1; w <= 32; w <<= 1) {
            d1 += __shfl_xor(d1, w); d2 += __shfl_xor(d2, w); ee += __shfl_xor(ee, w);
        }
        if (lane == 0) {
            double v1 = d1 / nc64[bi], v2 = d2 / nc64[si];
            int k; double v;
            if (v2 > v1 || (v2 == v1 && si < bi)) { k = si; v = v2; } else { k = bi; v = v1; }
            double nrm = fmax(sqrt(ee), (double)EPS);
            double ms = v / nrm;
            out_nov[row] = (float)(1.0 - ms * ms);
            out_cls[row] = (float)k;
        }
    }
}

__global__ void k_hist(const float* __restrict__ cls, int* __restrict__ cnt) {
    __shared__ int h[K_N];
    int t = threadIdx.x;
    if (t < K_N) h[t] = 0;
    __syncthreads();
    int b = blockIdx.x * 256 + t;
    atomicAdd(&h[(int)cls[b]], 1);
    __syncthreads();
    if (t < K_N && h[t] > 0) atomicAdd(&cnt[t], h[t]);
}

__global__ void k_prefix(const int* __restrict__ cnt, int* __restrict__ offs,
                         int* __restrict__ cur,
                         const float* __restrict__ counts_in, float* __restrict__ out_cnts) {
    if (threadIdx.x == 0) {
        int r = 0;
        for (int k = 0; k < K_N; k++) { offs[k] = r; cur[k] = r; r += cnt[k]; }
    }
    int t = threadIdx.x;
    if (t < K_N) out_cnts[t] = counts_in[t] + (float)cnt[t];
}

__global__ void k_scatter(const float* __restrict__ cls, int* __restrict__ cur,
                          unsigned* __restrict__ idx_buf) {
    __shared__ int h[K_N];
    __shared__ int basek[K_N];
    int t = threadIdx.x;
    if (t < K_N) h[t] = 0;
    __syncthreads();
    int b = blockIdx.x * 256 + t;
    int k = (int)cls[b];
    int lr = atomicAdd(&h[k], 1);
    __syncthreads();
    if (t < K_N && h[t] > 0) basek[t] = atomicAdd(&cur[t], h[t]);
    __syncthreads();
    idx_buf[basek[k] + lr] = (unsigned)b;
}

// ---- per-cluster segment sums: float4 loads, 4 rows in flight, LDS reduce ----
__global__ void k_segsum(const float* __restrict__ e, const unsigned* __restrict__ idx_buf,
                         const int* __restrict__ cnt, const int* __restrict__ offs,
                         double* __restrict__ partial, int seg) {
    __shared__ double red[3][96][4];
    int k = blockIdx.x, s = blockIdx.y, t = threadIdx.x;   // 384 threads
    int r4 = t / 96, c4 = t - r4 * 96;
    int n = cnt[k], base = offs[k];
    int i0 = (int)((long long)n * s / seg);
    int i1 = (int)((long long)n * (s + 1) / seg);
    double a0 = 0, a1 = 0, a2 = 0, a3 = 0;
    int i = i0 + r4;
    unsigned rn = (i < i1) ? idx_buf[base + i] : 0u;
    while (i < i1) {
        unsigned r = rn;
        int inext = i + 4;
        rn = (inext < i1) ? idx_buf[base + inext] : 0u;
        float4 v = *(const float4*)(e + (size_t)r * D_N + c4 * 4);
        a0 += v.x; a1 += v.y; a2 += v.z; a3 += v.w;
        i = inext;
    }
    if (r4 > 0) {
        red[r4 - 1][c4][0] = a0; red[r4 - 1][c4][1] = a1;
        red[r4 - 1][c4][2] = a2; red[r4 - 1][c4][3] = a3;
    }
    __syncthreads();
    if (r4 == 0) {
        a0 += red[0][c4][0] + red[1][c4][0] + red[2][c4][0];
        a1 += red[0][c4][1] + red[1][c4][1] + red[2][c4][1];
        a2 += red[0][c4][2] + red[1][c4][2] + red[2][c4][2];
        a3 += red[0][c4][3] + red[1][c4][3] + red[2][c4][3];
        double* p = partial + ((size_t)(k * seg + s)) * D_N + c4 * 4;
        p[0] = a0; p[1] = a1; p[2] = a2; p[3] = a3;
    }
}

__global__ void k_final(const float* __restrict__ c_raw, const double* __restrict__ partial,
                        const int* __restrict__ cnt, float* __restrict__ out_cent, int seg) {
    int idx = blockIdx.x * 256 + threadIdx.x;
    if (idx >= K_N * D_N) return;
    int k = idx / D_N;
    int d = idx - k * D_N;
    double sum = 0.0;
    for (int s = 0; s < seg; s++) sum += partial[((size_t)(k * seg + s)) * D_N + d];
    int n = cnt[k];
    float c0 = c_raw[idx];
    float mean = (float)(sum / (double)(n > 1 ? n : 1));
    out_cent[idx] = (n > 0) ? (MOM * c0 + (1.0f - MOM) * mean) : c0;
}

extern "C" void kernel_launch(void* const* d_in, const int* in_sizes, int n_in,
                              void* d_out, int out_size, void* d_ws, size_t ws_size,
                              hipStream_t stream) {
    const float* emb    = (const float*)d_in[0];
    const float* cen    = (const float*)d_in[1];
    const float* counts = (const float*)d_in[2];
    float* out = (float*)d_out;
    char* ws = (char*)d_ws;

    unsigned short* cpk     = (unsigned short*)(ws + OFF_CPK);
    double*         nc64    = (double*)(ws + OFF_NC64);
    int*            cnt     = (int*)(ws + OFF_CNT);
    int*            offs    = (int*)(ws + OFF_OFFS);
    int*            cur     = (int*)(ws + OFF_CUR);
    int*            flagn   = (int*)(ws + OFF_FLAGN);
    unsigned*       flags   = (unsigned*)(ws + OFF_FLAGS);
    unsigned*       idx_buf = (unsigned*)(ws + OFF_IDX);
    double*         partial = (double*)(ws + OFF_PART);

    int seg = SEG_MAX;
    while (seg > 1 && OFF_PART + (size_t)K_N * seg * D_N * 8 > ws_size) seg >>= 1;

    float* out_nov  = out;
    float* out_cls  = out + B_N;
    float* out_cent = out + 2 * B_N;
    float* out_cnts = out + 2 * B_N + K_N * D_N;

    k_norm_c<<<NPAD, 128, 0, stream>>>(cen, cpk, nc64);
    k_zero<<<1, 128, 0, stream>>>(cnt, flagn);
    k_main<<<B_N / 256, 512, 0, stream>>>(emb, cpk, out_nov, out_cls, flags, flagn);
    k_refine<<<256, 256, 0, stream>>>(emb, cen, nc64, flagn, flags, out_nov, out_cls);
    k_hist<<<B_N / 256, 256, 0, stream>>>(out_cls, cnt);
    k_prefix<<<1, 128, 0, stream>>>(cnt, offs, cur, counts, out_cnts);
    k_scatter<<<B_N / 256, 256, 0, stream>>>(out_cls, cur, idx_buf);
    k_segsum<<<dim3(K_N, seg), 384, 0, stream>>>(emb, idx_buf, cnt, offs, partial, seg);
    k_final<<<(K_N * D_N + 255) / 256, 256, 0, stream>>>(cen, partial, cnt, out_cent, seg);
}